// Round 3
// baseline (15917.679 us; speedup 1.0000x reference)
//
#include <hip/hip_runtime.h>
#include <math.h>

#define H        1024
#define TSTEPS   2048
#define NWG      256
#define NT       320           // 4 compute waves + 1 poll wave
#define PAD      68            // padded segment stride (floats)
#define SENT     0xFFFFFFFFu   // -NaN bit pattern: h,z can never be this

// Scattered hs layout: float index of element E at step t:
//   ((E>>4)*TSTEPS + t)*16 + (E&15)
// -> each 64B "line column" is a contiguous 128KB region; a row's 64 lines
//    spread across 64 such regions (many IC channels, no hotspot).

__device__ __forceinline__ float fsig(float x) { return 1.0f / (1.0f + __expf(-x)); }
__device__ __forceinline__ float ftanh(float x) { return 1.0f - 2.0f / (__expf(2.0f * x) + 1.0f); }

__global__ __launch_bounds__(NT, 1) void lstm_persistent(
    const float* __restrict__ z,   const float* __restrict__ Wih,
    const float* __restrict__ Whh, const float* __restrict__ b_ih,
    const float* __restrict__ b_hh,
    const float* __restrict__ W1,  const float* __restrict__ b1,
    const float* __restrict__ W2,  const float* __restrict__ b2,
    const float* __restrict__ W3,  const float* __restrict__ b3,
    float* __restrict__ out, float* __restrict__ hs)
{
    __shared__ __align__(16) float hbuf[2][16 * PAD];  // double-buffered h row
    __shared__ float a1_lds[32];
    __shared__ float a2_lds[32];

    const int tid = threadIdx.x;
    const int wg  = blockIdx.x;

    // ---- stage z into hbuf[1] (step-0 input) ----
    if (tid < 256) {
        float4 zv = *(const float4*)(z + tid * 4);
        *(float4*)(&hbuf[1][(tid >> 4) * PAD + (tid & 15) * 4]) = zv;
    }
    __syncthreads();                                    // B0

    if (tid < 256) {
        // ======== compute waves: wave w owns h-element wg*4+w ========
        const int w    = tid >> 6;        // element within WG (0..3)
        const int lane = tid & 63;
        const int g    = lane >> 4;       // gate 0=i,1=f,2=g,3=o
        const int seg  = lane & 15;       // 64-col segment
        const int grow = g * H + wg * 4 + w;
        const int E    = wg * 4 + w;
        unsigned* hrow_base = (unsigned*)hs + (size_t)(E >> 4) * TSTEPS * 16 + (E & 15);

        const float bias = b_ih[grow] + b_hh[grow];

        // weight load (combined Wc = Wih+Whh), fused step-0 dot with z
        float4 wreg[16];
        float acc = 0.f;
        const float* wihp = Wih + (size_t)grow * H + seg * 64;
        const float* whhp = Whh + (size_t)grow * H + seg * 64;
#pragma unroll
        for (int k = 0; k < 16; ++k) {
            float4 a  = *(const float4*)(wihp + 4 * k);
            float4 b  = *(const float4*)(whhp + 4 * k);
            float4 zz = *(const float4*)(&hbuf[1][seg * PAD + 4 * k]);
            acc += a.x * zz.x + a.y * zz.y + a.z * zz.z + a.w * zz.w;
            wreg[k] = make_float4(a.x + b.x, a.y + b.y, a.z + b.z, a.w + b.w);
        }
        acc += __shfl_xor(acc, 1); acc += __shfl_xor(acc, 2);
        acc += __shfl_xor(acc, 4); acc += __shfl_xor(acc, 8);
        acc += bias;
        {   // step 0: c_prev = 0
            float di = __shfl(acc, 0),  dg = __shfl(acc, 32), dd = __shfl(acc, 48);
            float c  = fsig(di) * ftanh(dg);
            float h  = fsig(dd) * ftanh(c);
            float c_reg = c;
            if (lane == 0)
                __hip_atomic_store(hrow_base + 0 * 16, __float_as_uint(h),
                                   __ATOMIC_RELAXED, __HIP_MEMORY_SCOPE_AGENT);

            // ---- main recurrence ----
            for (int t = 1; t < TSTEPS; ++t) {
                __syncthreads();                        // buf[(t-1)&1] ready
                const float* hb = &hbuf[(t - 1) & 1][seg * PAD];
                float a2 = 0.f;
#pragma unroll
                for (int k = 0; k < 16; ++k) {
                    float4 h4 = *(const float4*)(hb + 4 * k);
                    float4 wv = wreg[k];
                    a2 += wv.x * h4.x + wv.y * h4.y + wv.z * h4.z + wv.w * h4.w;
                }
                a2 += __shfl_xor(a2, 1); a2 += __shfl_xor(a2, 2);
                a2 += __shfl_xor(a2, 4); a2 += __shfl_xor(a2, 8);
                a2 += bias;
                float gi = __shfl(a2, 0),  gf = __shfl(a2, 16);
                float gg = __shfl(a2, 32), go = __shfl(a2, 48);
                float cn = fsig(gf) * c_reg + fsig(gi) * ftanh(gg);
                float hn = fsig(go) * ftanh(cn);
                c_reg = cn;
                if (lane == 0)
                    __hip_atomic_store(hrow_base + (size_t)t * 16, __float_as_uint(hn),
                                       __ATOMIC_RELAXED, __HIP_MEMORY_SCOPE_AGENT);
            }
        }
    } else {
        // ======== wave 4: poller — fills hbuf[t&1] with row t ========
        const int l = tid - 256;          // line 0..63 (16 floats each)
        const unsigned long long* lbase =
            (const unsigned long long*)((const unsigned*)hs + (size_t)l * TSTEPS * 16);
        float* dst0 = &hbuf[0][(l >> 2) * PAD + (l & 3) * 16];
        float* dst1 = &hbuf[1][(l >> 2) * PAD + (l & 3) * 16];
        for (int t = 0; t < TSTEPS - 1; ++t) {          // rows 0..2046
            const unsigned long long* p = lbase + (size_t)t * 8;
            unsigned long long v[8];
            int spin = 0;
            for (;;) {
                bool ok = true;
#pragma unroll
                for (int k = 0; k < 8; ++k) {
                    v[k] = __hip_atomic_load(p + k, __ATOMIC_RELAXED,
                                             __HIP_MEMORY_SCOPE_AGENT);
                    ok &= ((unsigned)v[k] != SENT) && ((unsigned)(v[k] >> 32) != SENT);
                }
                if (ok) break;
                if (((++spin) & 2047) == 0) __threadfence();
            }
            float* dst = (t & 1) ? dst1 : dst0;
#pragma unroll
            for (int k = 0; k < 8; ++k) {
                ((float*)dst)[2 * k]     = __uint_as_float((unsigned)v[k]);
                ((float*)dst)[2 * k + 1] = __uint_as_float((unsigned)(v[k] >> 32));
            }
            __syncthreads();                            // row t staged
        }
    }

    // ======== MLP tail: WG handles rows wg*8 .. wg*8+7 ========
    const int row = tid >> 3;   // 0..31 (tid<256)
    const int sub = tid & 7;    // 0..7
    for (int ti = 0; ti < 8; ++ti) {
        int t = wg * 8 + ti;
        __syncthreads();                                // prior LDS use done
        if (tid >= 256) {                               // poller fills hbuf[0]
            const int l = tid - 256;
            const unsigned long long* p =
                (const unsigned long long*)((const unsigned*)hs +
                    (size_t)l * TSTEPS * 16) + (size_t)t * 8;
            unsigned long long v[8];
            int spin = 0;
            for (;;) {
                bool ok = true;
#pragma unroll
                for (int k = 0; k < 8; ++k) {
                    v[k] = __hip_atomic_load(p + k, __ATOMIC_RELAXED,
                                             __HIP_MEMORY_SCOPE_AGENT);
                    ok &= ((unsigned)v[k] != SENT) && ((unsigned)(v[k] >> 32) != SENT);
                }
                if (ok) break;
                if (((++spin) & 2047) == 0) __threadfence();
            }
            float* dst = &hbuf[0][(l >> 2) * PAD + (l & 3) * 16];
#pragma unroll
            for (int k = 0; k < 8; ++k) {
                dst[2 * k]     = __uint_as_float((unsigned)v[k]);
                dst[2 * k + 1] = __uint_as_float((unsigned)(v[k] >> 32));
            }
        }
        __syncthreads();                                // row staged

        float acc1 = 0.f;
        if (tid < 256) {
            const float* w1p = W1 + (size_t)row * H + sub * 128;
#pragma unroll
            for (int k = 0; k < 32; ++k) {
                float4 wv = *(const float4*)(w1p + 4 * k);
                int c = sub * 128 + 4 * k;
                float4 h4 = *(const float4*)(&hbuf[0][(c >> 6) * PAD + (c & 63)]);
                acc1 += wv.x * h4.x + wv.y * h4.y + wv.z * h4.z + wv.w * h4.w;
            }
            acc1 += __shfl_xor(acc1, 1); acc1 += __shfl_xor(acc1, 2);
            acc1 += __shfl_xor(acc1, 4);
            if (sub == 0) a1_lds[row] = fmaxf(acc1 + b1[row], 0.f);
        }
        __syncthreads();                                // a1 ready

        if (tid < 32) {
            float a = 0.f;
#pragma unroll
            for (int k = 0; k < 32; ++k) a += W2[tid * 32 + k] * a1_lds[k];
            a2_lds[tid] = fmaxf(a + b2[tid], 0.f);
        }
        __syncthreads();                                // a2 ready

        if (tid < 64) {
            float a = 0.f;
#pragma unroll
            for (int k = 0; k < 32; ++k) a += W3[tid * 32 + k] * a2_lds[k];
            out[(size_t)t * 64 + tid] = a + b3[tid];
        }
    }
}

extern "C" void kernel_launch(void* const* d_in, const int* in_sizes, int n_in,
                              void* d_out, int out_size, void* d_ws, size_t ws_size,
                              hipStream_t stream) {
    const float* z    = (const float*)d_in[0];
    const float* Wih  = (const float*)d_in[1];
    const float* Whh  = (const float*)d_in[2];
    const float* b_ih = (const float*)d_in[3];
    const float* b_hh = (const float*)d_in[4];
    const float* W1   = (const float*)d_in[5];
    const float* b1   = (const float*)d_in[6];
    const float* W2   = (const float*)d_in[7];
    const float* b2   = (const float*)d_in[8];
    const float* W3   = (const float*)d_in[9];
    const float* b3   = (const float*)d_in[10];
    float* out = (float*)d_out;

    float* hs = (float*)d_ws;   // TSTEPS*H floats = 8 MB, scattered layout

    hipMemsetAsync(hs, 0xFF, (size_t)TSTEPS * H * sizeof(float), stream);
    hipLaunchKernelGGL(lstm_persistent, dim3(NWG), dim3(NT), 0, stream,
                       z, Wih, Whh, b_ih, b_hh, W1, b1, W2, b2, W3, b3,
                       out, hs);
}

// Round 4
// 8519.357 us; speedup vs baseline: 1.8684x; 1.8684x over previous
//
#include <hip/hip_runtime.h>
#include <math.h>

#define H        1024
#define TSTEPS   2048
#define NWG      256
#define NT       256
#define PAD      68            // padded segment stride (floats): bank-conflict-free
#define SENT     0xFFFFFFFFu   // -NaN bit pattern: h can never be this

typedef unsigned u32x4 __attribute__((ext_vector_type(4)));

// One 16B cache-bypassing load (same sc0/sc1 semantics the compiler emits for
// relaxed AGENT atomics, but a single dwordx4 request instead of two u64s).
__device__ __forceinline__ u32x4 load16_bypass(const unsigned* p) {
    u32x4 r;
    asm volatile("global_load_dwordx4 %0, %1, off sc0 sc1\n\ts_waitcnt vmcnt(0)"
                 : "=v"(r) : "v"(p) : "memory");
    return r;
}

__device__ __forceinline__ float fsig(float x)   { return 1.0f / (1.0f + __expf(-x)); }
__device__ __forceinline__ float ftanh_(float x) { return 1.0f - 2.0f / (__expf(2.0f * x) + 1.0f); }

__global__ __launch_bounds__(NT, 1) void lstm_persistent(
    const float* __restrict__ z,   const float* __restrict__ Wih,
    const float* __restrict__ Whh, const float* __restrict__ b_ih,
    const float* __restrict__ b_hh,
    const float* __restrict__ W1,  const float* __restrict__ b1,
    const float* __restrict__ W2,  const float* __restrict__ b2,
    const float* __restrict__ W3,  const float* __restrict__ b3,
    float* __restrict__ out, float* __restrict__ hs)
{
    __shared__ __align__(16) float hbuf[2][16 * PAD];  // double-buffered h row
    __shared__ float a1_lds[32];
    __shared__ float a2_lds[32];

    const int tid  = threadIdx.x;
    const int wg   = blockIdx.x;
    const int w    = tid >> 6;        // wave = element within WG (0..3)
    const int lane = tid & 63;
    const int g    = lane >> 4;       // gate 0=i,1=f,2=g,3=o
    const int seg  = lane & 15;       // 64-col segment
    const int grow = g * H + wg * 4 + w;
    const float bias = b_ih[grow] + b_hh[grow];

    // ---- stage z -> hbuf[0] ----
    {
        float4 zv = *(const float4*)(z + tid * 4);
        *(float4*)(&hbuf[0][(tid >> 4) * PAD + (tid & 15) * 4]) = zv;
    }
    __syncthreads();

    // ---- weights (Wc = Wih+Whh) into regs; fused step-0 dot (x=z, c=h=0) ----
    float4 wreg[16];
    float s0 = 0.f, s1 = 0.f, s2 = 0.f, s3 = 0.f;
    const float* wihp = Wih + (size_t)grow * H + seg * 64;
    const float* whhp = Whh + (size_t)grow * H + seg * 64;
#pragma unroll
    for (int k = 0; k < 16; ++k) {
        float4 a  = *(const float4*)(wihp + 4 * k);
        float4 b  = *(const float4*)(whhp + 4 * k);
        float4 zz = *(const float4*)(&hbuf[0][seg * PAD + 4 * k]);
        float d = a.x * zz.x + a.y * zz.y + a.z * zz.z + a.w * zz.w;
        if ((k & 3) == 0) s0 += d; else if ((k & 3) == 1) s1 += d;
        else if ((k & 3) == 2) s2 += d; else s3 += d;
        wreg[k] = make_float4(a.x + b.x, a.y + b.y, a.z + b.z, a.w + b.w);
    }
    float acc = (s0 + s1) + (s2 + s3);
    acc += __shfl_xor(acc, 1); acc += __shfl_xor(acc, 2);
    acc += __shfl_xor(acc, 4); acc += __shfl_xor(acc, 8);
    acc += bias;
    float c_reg;
    {
        float gi = __shfl(acc, 0), gg = __shfl(acc, 32), go = __shfl(acc, 48);
        float c = fsig(gi) * ftanh_(gg);          // c_prev = 0
        float h = fsig(go) * ftanh_(c);
        c_reg = c;
        if (lane == 0)
            __hip_atomic_store((unsigned*)hs + wg * 4 + w, __float_as_uint(h),
                               __ATOMIC_RELAXED, __HIP_MEMORY_SCOPE_AGENT);
    }

    // ---- main recurrence: self-polling dataflow sync, 1 barrier/step ----
    for (int t = 1; t < TSTEPS; ++t) {
        const unsigned* p = (const unsigned*)hs + (size_t)(t - 1) * H + tid * 4;
        u32x4 v;
        for (;;) {
            v = load16_bypass(p);
            if (v.x != SENT && v.y != SENT && v.z != SENT && v.w != SENT) break;
        }
        float* dst = &hbuf[t & 1][(tid >> 4) * PAD + (tid & 15) * 4];
        dst[0] = __uint_as_float(v.x); dst[1] = __uint_as_float(v.y);
        dst[2] = __uint_as_float(v.z); dst[3] = __uint_as_float(v.w);
        __syncthreads();                           // row staged; prev buf WAR-safe

        const float* hb = &hbuf[t & 1][seg * PAD];
        float q0 = 0.f, q1 = 0.f, q2 = 0.f, q3 = 0.f;
#pragma unroll
        for (int k = 0; k < 16; ++k) {
            float4 h4 = *(const float4*)(hb + 4 * k);
            float4 wv = wreg[k];
            float d = wv.x * h4.x + wv.y * h4.y + wv.z * h4.z + wv.w * h4.w;
            if ((k & 3) == 0) q0 += d; else if ((k & 3) == 1) q1 += d;
            else if ((k & 3) == 2) q2 += d; else q3 += d;
        }
        float a2 = (q0 + q1) + (q2 + q3);
        a2 += __shfl_xor(a2, 1); a2 += __shfl_xor(a2, 2);
        a2 += __shfl_xor(a2, 4); a2 += __shfl_xor(a2, 8);
        a2 += bias;
        float gi = __shfl(a2, 0),  gf = __shfl(a2, 16);
        float gg = __shfl(a2, 32), go = __shfl(a2, 48);
        float cn = fsig(gf) * c_reg + fsig(gi) * ftanh_(gg);
        float hn = fsig(go) * ftanh_(cn);
        c_reg = cn;
        if (lane == 0)
            __hip_atomic_store((unsigned*)(hs + (size_t)t * H) + wg * 4 + w,
                               __float_as_uint(hn),
                               __ATOMIC_RELAXED, __HIP_MEMORY_SCOPE_AGENT);
    }

    // ---- MLP tail: WG handles rows wg*8 .. wg*8+7 (poll for stragglers) ----
    const int row = tid >> 3;   // 0..31
    const int sub = tid & 7;    // 0..7
    for (int ti = 0; ti < 8; ++ti) {
        int t = wg * 8 + ti;
        __syncthreads();                           // prior LDS use done
        {
            const unsigned* p = (const unsigned*)hs + (size_t)t * H + tid * 4;
            u32x4 v;
            for (;;) {
                v = load16_bypass(p);
                if (v.x != SENT && v.y != SENT && v.z != SENT && v.w != SENT) break;
            }
            float* dst = &hbuf[0][(tid >> 4) * PAD + (tid & 15) * 4];
            dst[0] = __uint_as_float(v.x); dst[1] = __uint_as_float(v.y);
            dst[2] = __uint_as_float(v.z); dst[3] = __uint_as_float(v.w);
        }
        __syncthreads();                           // row staged

        float acc1 = 0.f;
        const float* w1p = W1 + (size_t)row * H + sub * 128;
#pragma unroll
        for (int k = 0; k < 32; ++k) {
            float4 wv = *(const float4*)(w1p + 4 * k);
            int c = sub * 128 + 4 * k;
            float4 h4 = *(const float4*)(&hbuf[0][(c >> 6) * PAD + (c & 63)]);
            acc1 += wv.x * h4.x + wv.y * h4.y + wv.z * h4.z + wv.w * h4.w;
        }
        acc1 += __shfl_xor(acc1, 1); acc1 += __shfl_xor(acc1, 2); acc1 += __shfl_xor(acc1, 4);
        if (sub == 0) a1_lds[row] = fmaxf(acc1 + b1[row], 0.f);
        __syncthreads();                           // a1 ready

        if (tid < 32) {
            float a = 0.f;
#pragma unroll
            for (int k = 0; k < 32; ++k) a += W2[tid * 32 + k] * a1_lds[k];
            a2_lds[tid] = fmaxf(a + b2[tid], 0.f);
        }
        __syncthreads();                           // a2 ready

        if (tid < 64) {
            float a = 0.f;
#pragma unroll
            for (int k = 0; k < 32; ++k) a += W3[tid * 32 + k] * a2_lds[k];
            out[(size_t)t * 64 + tid] = a + b3[tid];
        }
    }
}

extern "C" void kernel_launch(void* const* d_in, const int* in_sizes, int n_in,
                              void* d_out, int out_size, void* d_ws, size_t ws_size,
                              hipStream_t stream) {
    const float* z    = (const float*)d_in[0];
    const float* Wih  = (const float*)d_in[1];
    const float* Whh  = (const float*)d_in[2];
    const float* b_ih = (const float*)d_in[3];
    const float* b_hh = (const float*)d_in[4];
    const float* W1   = (const float*)d_in[5];
    const float* b1   = (const float*)d_in[6];
    const float* W2   = (const float*)d_in[7];
    const float* b2   = (const float*)d_in[8];
    const float* W3   = (const float*)d_in[9];
    const float* b3   = (const float*)d_in[10];
    float* out = (float*)d_out;

    float* hs = (float*)d_ws;   // TSTEPS*H floats = 8 MB, contiguous rows

    // Sentinel-fill hs: 0xFF bytes -> -NaN, unreachable as h.
    hipMemsetAsync(hs, 0xFF, (size_t)TSTEPS * H * sizeof(float), stream);
    hipLaunchKernelGGL(lstm_persistent, dim3(NWG), dim3(NT), 0, stream,
                       z, Wih, Whh, b_ih, b_hh, W1, b1, W2, b2, W3, b3,
                       out, hs);
}

// Round 5
// 4119.625 us; speedup vs baseline: 3.8639x; 2.0680x over previous
//
#include <hip/hip_runtime.h>
#include <math.h>

#define H        1024
#define TSTEPS   2048
#define NWG      64
#define NT       1024
#define PAD      68            // padded segment stride (floats)
#define SENT     0xFFFFFFFFu   // -NaN bit pattern: h can never be this

typedef unsigned u32x4 __attribute__((ext_vector_type(4)));

// 16B AGENT-scope load (sc1 only -- matches compiler's relaxed-agent atomic;
// sc0+sc1 would be system scope, measured 1.55x slower in R4).
__device__ __forceinline__ u32x4 load16_agent(const unsigned* p) {
    u32x4 r;
    asm volatile("global_load_dwordx4 %0, %1, off sc1\n\ts_waitcnt vmcnt(0)"
                 : "=v"(r) : "v"(p) : "memory");
    return r;
}

__device__ __forceinline__ float fsig(float x)   { return 1.0f / (1.0f + __expf(-x)); }
__device__ __forceinline__ float ftanh_(float x) { return 1.0f - 2.0f / (__expf(2.0f * x) + 1.0f); }

__global__ __launch_bounds__(NT, 1) void lstm_persistent(
    const float* __restrict__ z,   const float* __restrict__ Wih,
    const float* __restrict__ Whh, const float* __restrict__ b_ih,
    const float* __restrict__ b_hh,
    const float* __restrict__ W1,  const float* __restrict__ b1,
    const float* __restrict__ W2,  const float* __restrict__ b2,
    const float* __restrict__ W3,  const float* __restrict__ b3,
    float* __restrict__ out, float* __restrict__ hs)
{
    __shared__ __align__(16) float hbuf[2][16 * PAD];   // double-buffered h row
    __shared__ __align__(16) float mlp_buf[4][16 * PAD];
    __shared__ float gates_lds[64];
    __shared__ float a1_lds[4][32];
    __shared__ float a2_lds[4][32];

    const int tid = threadIdx.x;
    const int wg  = blockIdx.x;
    const int r   = tid >> 4;        // local gate row 0..63
    const int seg = tid & 15;        // 64-col segment
    const int g   = r >> 4;          // gate 0=i,1=f,2=g,3=o
    const int e   = r & 15;          // element within WG (0..15)
    const int grow = g * H + wg * 16 + e;
    const float bias = b_ih[grow] + b_hh[grow];

    // ---- stage z -> hbuf[0] ----
    if (tid < 256) {
        float4 zv = *(const float4*)(z + tid * 4);
        *(float4*)(&hbuf[0][(tid >> 4) * PAD + (tid & 15) * 4]) = zv;
    }
    __syncthreads();

    // ---- weights (Wc = Wih+Whh) into regs; fused step-0 dot (x=z, h=c=0) ----
    float4 wreg[16];
    float s0 = 0.f, s1 = 0.f, s2 = 0.f, s3 = 0.f;
    const float* wihp = Wih + (size_t)grow * H + seg * 64;
    const float* whhp = Whh + (size_t)grow * H + seg * 64;
#pragma unroll
    for (int k = 0; k < 16; ++k) {
        float4 a  = *(const float4*)(wihp + 4 * k);
        float4 b  = *(const float4*)(whhp + 4 * k);
        float4 zz = *(const float4*)(&hbuf[0][seg * PAD + 4 * k]);
        float d = a.x * zz.x + a.y * zz.y + a.z * zz.z + a.w * zz.w;
        if ((k & 3) == 0) s0 += d; else if ((k & 3) == 1) s1 += d;
        else if ((k & 3) == 2) s2 += d; else s3 += d;
        wreg[k] = make_float4(a.x + b.x, a.y + b.y, a.z + b.z, a.w + b.w);
    }
    {
        float acc = (s0 + s1) + (s2 + s3);
        acc += __shfl_xor(acc, 1); acc += __shfl_xor(acc, 2);
        acc += __shfl_xor(acc, 4); acc += __shfl_xor(acc, 8);
        if (seg == 0) gates_lds[r] = acc + bias;
    }
    __syncthreads();

    float c_reg = 0.f;   // live in wave 15, lanes 0..15 (element = lane)
    if (tid >= 960 && tid < 976) {
        int el = tid - 960;
        float gi = gates_lds[el],      gg = gates_lds[32 + el], go = gates_lds[48 + el];
        float c = fsig(gi) * ftanh_(gg);           // c_prev = 0
        float h = fsig(go) * ftanh_(c);
        c_reg = c;
        __hip_atomic_store((unsigned*)hs + wg * 16 + el, __float_as_uint(h),
                           __ATOMIC_RELAXED, __HIP_MEMORY_SCOPE_AGENT);
    }

    // ---- main recurrence ----
    for (int t = 1; t < TSTEPS; ++t) {
        if (tid < 256) {   // pollers: waves 0..3 (cell wave 15 is NOT a poller)
            const unsigned* p = (const unsigned*)hs + (size_t)(t - 1) * H + tid * 4;
            u32x4 v;
            for (;;) {
                v = load16_agent(p);
                if (v.x != SENT && v.y != SENT && v.z != SENT && v.w != SENT) break;
            }
            float* dst = &hbuf[t & 1][(tid >> 4) * PAD + (tid & 15) * 4];
            dst[0] = __uint_as_float(v.x); dst[1] = __uint_as_float(v.y);
            dst[2] = __uint_as_float(v.z); dst[3] = __uint_as_float(v.w);
        }
        __syncthreads();                           // B1: row staged

        const float* hb = &hbuf[t & 1][seg * PAD];
        float q0 = 0.f, q1 = 0.f, q2 = 0.f, q3 = 0.f;
#pragma unroll
        for (int k = 0; k < 16; ++k) {
            float4 h4 = *(const float4*)(hb + 4 * k);
            float4 wv = wreg[k];
            float d = wv.x * h4.x + wv.y * h4.y + wv.z * h4.z + wv.w * h4.w;
            if ((k & 3) == 0) q0 += d; else if ((k & 3) == 1) q1 += d;
            else if ((k & 3) == 2) q2 += d; else q3 += d;
        }
        float a2 = (q0 + q1) + (q2 + q3);
        a2 += __shfl_xor(a2, 1); a2 += __shfl_xor(a2, 2);
        a2 += __shfl_xor(a2, 4); a2 += __shfl_xor(a2, 8);
        if (seg == 0) gates_lds[r] = a2 + bias;
        __syncthreads();                           // B2: gates ready

        if (tid >= 960 && tid < 976) {             // cell + 64B coalesced store
            int el = tid - 960;
            float gi = gates_lds[el],      gf = gates_lds[16 + el];
            float gg = gates_lds[32 + el], go = gates_lds[48 + el];
            float cn = fsig(gf) * c_reg + fsig(gi) * ftanh_(gg);
            float hn = fsig(go) * ftanh_(cn);
            c_reg = cn;
            __hip_atomic_store((unsigned*)(hs + (size_t)t * H) + wg * 16 + el,
                               __float_as_uint(hn),
                               __ATOMIC_RELAXED, __HIP_MEMORY_SCOPE_AGENT);
        }
    }

    // ---- MLP tail: 4 groups x 256 threads, each group one row at a time ----
    const int local = tid & 255;
    const int grp   = tid >> 8;      // 0..3
    const int row32 = local >> 3;    // 0..31
    const int sub   = local & 7;     // 0..7
    for (int ti = 0; ti < 8; ++ti) {
        int t = wg * 32 + ti * 4 + grp;
        __syncthreads();                           // WAR: prior mlp_buf/a_lds use
        {
            const unsigned* p = (const unsigned*)hs + (size_t)t * H + local * 4;
            u32x4 v;
            for (;;) {
                v = load16_agent(p);
                if (v.x != SENT && v.y != SENT && v.z != SENT && v.w != SENT) break;
            }
            float* dst = &mlp_buf[grp][(local >> 4) * PAD + (local & 15) * 4];
            dst[0] = __uint_as_float(v.x); dst[1] = __uint_as_float(v.y);
            dst[2] = __uint_as_float(v.z); dst[3] = __uint_as_float(v.w);
        }
        __syncthreads();                           // row staged

        float acc1 = 0.f;
        const float* w1p = W1 + (size_t)row32 * H + sub * 128;
#pragma unroll
        for (int k = 0; k < 32; ++k) {
            float4 wv = *(const float4*)(w1p + 4 * k);
            int c = sub * 128 + 4 * k;
            float4 h4 = *(const float4*)(&mlp_buf[grp][(c >> 6) * PAD + (c & 63)]);
            acc1 += wv.x * h4.x + wv.y * h4.y + wv.z * h4.z + wv.w * h4.w;
        }
        acc1 += __shfl_xor(acc1, 1); acc1 += __shfl_xor(acc1, 2); acc1 += __shfl_xor(acc1, 4);
        if (sub == 0) a1_lds[grp][row32] = fmaxf(acc1 + b1[row32], 0.f);
        __syncthreads();                           // a1 ready

        if (local < 32) {
            float a = 0.f;
#pragma unroll
            for (int k = 0; k < 32; ++k) a += W2[local * 32 + k] * a1_lds[grp][k];
            a2_lds[grp][local] = fmaxf(a + b2[local], 0.f);
        }
        __syncthreads();                           // a2 ready

        if (local < 64) {
            float a = 0.f;
#pragma unroll
            for (int k = 0; k < 32; ++k) a += W3[local * 32 + k] * a2_lds[grp][k];
            out[(size_t)t * 64 + local] = a + b3[local];
        }
    }
}

extern "C" void kernel_launch(void* const* d_in, const int* in_sizes, int n_in,
                              void* d_out, int out_size, void* d_ws, size_t ws_size,
                              hipStream_t stream) {
    const float* z    = (const float*)d_in[0];
    const float* Wih  = (const float*)d_in[1];
    const float* Whh  = (const float*)d_in[2];
    const float* b_ih = (const float*)d_in[3];
    const float* b_hh = (const float*)d_in[4];
    const float* W1   = (const float*)d_in[5];
    const float* b1   = (const float*)d_in[6];
    const float* W2   = (const float*)d_in[7];
    const float* b2   = (const float*)d_in[8];
    const float* W3   = (const float*)d_in[9];
    const float* b3   = (const float*)d_in[10];
    float* out = (float*)d_out;

    float* hs = (float*)d_ws;   // TSTEPS*H floats = 8 MB, contiguous rows

    // Sentinel-fill hs: 0xFF bytes -> -NaN, unreachable as h.
    hipMemsetAsync(hs, 0xFF, (size_t)TSTEPS * H * sizeof(float), stream);
    hipLaunchKernelGGL(lstm_persistent, dim3(NWG), dim3(NT), 0, stream,
                       z, Wih, Whh, b_ih, b_hh, W1, b1, W2, b2, W3, b3,
                       out, hs);
}